// Round 7
// baseline (580.372 us; speedup 1.0000x reference)
//
#include <hip/hip_runtime.h>
#include <hip/hip_bf16.h>
#include <math.h>

constexpr int N_NODES = 50000;
constexpr int HD = 64;

// ---------- histogram: cnt[d]++ ----------
__global__ __launch_bounds__(256) void hist_kernel(const int* __restrict__ dst,
                                                   int* __restrict__ cnt, int E) {
    int i = blockIdx.x * blockDim.x + threadIdx.x;
    if (i < E) atomicAdd(&cnt[dst[i]], 1);
}

// ---------- exclusive scan of cnt -> off (single block, 256 threads) ----------
__global__ __launch_bounds__(256) void scan_kernel(const int* __restrict__ cnt,
                                                   int* __restrict__ off, int N) {
    const int t = threadIdx.x;
    const int chunk = (N + 255) / 256;             // 196
    const int beg = t * chunk;
    const int end = min(beg + chunk, N);
    int s = 0;
    for (int i = beg; i < end; ++i) s += cnt[i];
    const int lane = t & 63, wid = t >> 6;
    // inclusive scan within wave
    int incl = s;
#pragma unroll
    for (int o = 1; o <= 32; o <<= 1) {
        int v = __shfl_up(incl, o);
        if (lane >= o) incl += v;
    }
    __shared__ int wtot[4];
    if (lane == 63) wtot[wid] = incl;
    __syncthreads();
    int base = 0;
    for (int w = 0; w < wid; ++w) base += wtot[w];
    int run = base + incl - s;                     // exclusive prefix of this chunk
    for (int i = beg; i < end; ++i) { off[i] = run; run += cnt[i]; }
    if (t == 255) off[N] = run;
}

__global__ __launch_bounds__(256) void dis_kernel(const int* __restrict__ cnt,
                                                  float* __restrict__ dis, int N) {
    int i = blockIdx.x * blockDim.x + threadIdx.x;
    if (i < N) dis[i] = rsqrtf((float)cnt[i] + 1.0f);
}

// ---------- CSR fill: csr[off[d] + slot] = src ----------
__global__ __launch_bounds__(256) void fill_kernel(const int* __restrict__ src,
                                                   const int* __restrict__ dst,
                                                   const int* __restrict__ off,
                                                   int* __restrict__ cur,
                                                   int* __restrict__ csr, int E) {
    int i = blockIdx.x * blockDim.x + threadIdx.x;
    if (i < E) {
        int d = dst[i];
        int slot = atomicAdd(&cur[d], 1);
        csr[off[d] + slot] = src[i];
    }
}

// ---------- GEMM: out[n][j] = sum_k in[n][k] * W[k][j] ----------
// Block = 64 rows x 64 cols. lane = row, wave = 16-col block.
// x: per-lane float4 stream (rows of a block share L1 lines).
// W: wave-uniform address -> s_load; inner op v_fmac_f32 acc, s_w, v_x.
template <int K>
__global__ __launch_bounds__(256) void gemm_kernel(const float* __restrict__ in,
                                                   const float* __restrict__ W,
                                                   float* __restrict__ out, int N) {
    const int lane = threadIdx.x & 63;
    const int wid  = threadIdx.x >> 6;
    const int row  = blockIdx.x * 64 + lane;
    const int c0   = wid * 16;
    const bool valid = row < N;
    const float* __restrict__ xr = in + (size_t)(valid ? row : 0) * K;
    float acc[16];
#pragma unroll
    for (int c = 0; c < 16; ++c) acc[c] = 0.f;
#pragma unroll
    for (int kq = 0; kq < K / 4; ++kq) {
        const float4 xv = *(const float4*)(xr + kq * 4);
#pragma unroll
        for (int kk = 0; kk < 4; ++kk) {
            const float xk = (&xv.x)[kk];
            const int k = kq * 4 + kk;
#pragma unroll
            for (int c = 0; c < 16; ++c)
                acc[c] = fmaf(xk, W[k * HD + c0 + c], acc[c]);
        }
    }
    if (valid) {
        float4* op = (float4*)(out + (size_t)row * HD + c0);
#pragma unroll
        for (int c4 = 0; c4 < 4; ++c4)
            op[c4] = make_float4(acc[c4 * 4], acc[c4 * 4 + 1], acc[c4 * 4 + 2], acc[c4 * 4 + 3]);
    }
}

// ---------- fused aggregation, 4-edge-wide float4 gathers (CSR) ----------
__global__ __launch_bounds__(256) void agg_kernel(const int* __restrict__ csr,
                                                  const int* __restrict__ off,
                                                  const float* __restrict__ dis,
                                                  const float* __restrict__ hw,
                                                  const float* __restrict__ b,
                                                  float* __restrict__ out,
                                                  __hip_bfloat16* __restrict__ out16, int N) {
    const int lane = threadIdx.x & 63;
    const int wid  = threadIdx.x >> 6;
    const int n = blockIdx.x * 4 + wid;
    if (n >= N) return;
    const int beg = off[n];
    const int c = min(off[n + 1] - beg, 64);
    int   s_l = 0;
    float w_l = 0.f;
    if (lane < c) {
        s_l = csr[beg + lane];
        w_l = dis[s_l];
    }
    const float dn = dis[n];
    const int g = lane >> 4;
    const int p = lane & 15;
    float ax = 0.f, ay = 0.f, az = 0.f, aw = 0.f;
    for (int e = 0; e < c; e += 4) {
        const int   ee = e + g;
        const int   sE = __shfl(s_l, ee);   // ee<c -> real src; else s_l=0 (valid row), w=0
        const float wE = __shfl(w_l, ee);
        const float4 hv = *(const float4*)(hw + (size_t)sE * HD + p * 4);
        ax = fmaf(hv.x, wE, ax);
        ay = fmaf(hv.y, wE, ay);
        az = fmaf(hv.z, wE, az);
        aw = fmaf(hv.w, wE, aw);
    }
#pragma unroll
    for (int st = 16; st <= 32; st <<= 1) {
        ax += __shfl_xor(ax, st);
        ay += __shfl_xor(ay, st);
        az += __shfl_xor(az, st);
        aw += __shfl_xor(aw, st);
    }
    if (g == 0) {
        const float4 self = *(const float4*)(hw + (size_t)n * HD + p * 4);
        const float4 bv   = *(const float4*)(b + p * 4);
        float4 v;
        v.x = fmaxf(fmaf(ax + self.x * dn, dn, bv.x), 0.f);
        v.y = fmaxf(fmaf(ay + self.y * dn, dn, bv.y), 0.f);
        v.z = fmaxf(fmaf(az + self.z * dn, dn, bv.z), 0.f);
        v.w = fmaxf(fmaf(aw + self.w * dn, dn, bv.w), 0.f);
        *(float4*)(out + (size_t)n * HD + p * 4) = v;
        ushort4 o16;
        __hip_bfloat16 t0 = __float2bfloat16(v.x);
        __hip_bfloat16 t1 = __float2bfloat16(v.y);
        __hip_bfloat16 t2 = __float2bfloat16(v.z);
        __hip_bfloat16 t3 = __float2bfloat16(v.w);
        o16.x = *(unsigned short*)&t0;
        o16.y = *(unsigned short*)&t1;
        o16.z = *(unsigned short*)&t2;
        o16.w = *(unsigned short*)&t3;
        *(ushort4*)((unsigned short*)out16 + (size_t)n * HD + p * 4) = o16;
    }
}

// ---------- u-precompute: u16[n][h][m] = bf16( sum_l Wp[l*4+m] * zs16[l][n][h] ) ----------
__global__ __launch_bounds__(256) void uprep_kernel(const __hip_bfloat16* __restrict__ zs16,
                                                    const float* __restrict__ Wp,
                                                    ushort4* __restrict__ u16, int N) {
    const int i = blockIdx.x * blockDim.x + threadIdx.x;
    const int total = N * HD;
    if (i >= total) return;
    const size_t NH = (size_t)N_NODES * HD;
    float z0 = __bfloat162float(zs16[0 * NH + i]);
    float z1 = __bfloat162float(zs16[1 * NH + i]);
    float z2 = __bfloat162float(zs16[2 * NH + i]);
    float z3 = __bfloat162float(zs16[3 * NH + i]);
    ushort4 r;
    unsigned short* rp = (unsigned short*)&r;
#pragma unroll
    for (int m = 0; m < 4; ++m) {
        float um = z0 * Wp[0 * 4 + m] + z1 * Wp[1 * 4 + m] + z2 * Wp[2 * 4 + m] + z3 * Wp[3 * 4 + m];
        __hip_bfloat16 bv = __float2bfloat16(um);
        rp[m] = *(unsigned short*)&bv;
    }
    u16[i] = r;
}

// ---------- link prediction + BCE loss: 8 edges per wave-iteration ----------
__global__ __launch_bounds__(256) void linkpred_kernel(const ushort4* __restrict__ u16,
                                                       const unsigned short* __restrict__ zs16,
                                                       const int* __restrict__ pos,
                                                       const int* __restrict__ neg,
                                                       const float* __restrict__ bp,
                                                       double* __restrict__ acc, int EP) {
    const int lane = threadIdx.x & 63;
    const int wid  = threadIdx.x >> 6;
    const size_t NH = (size_t)N_NODES * HD;
    const float bpv = bp[0];
    int gw = blockIdx.x * 4 + wid;
    const int nw = gridDim.x * 4;
    const int nchunks = (2 * EP) >> 3;
    float lsum = 0.f;
    for (int c0 = gw; c0 < nchunks; c0 += nw) {
        const int c = __builtin_amdgcn_readfirstlane(c0);
        const int i0 = c << 3;
        const bool is_pos = i0 < EP;
        const int* __restrict__ eptr = is_pos ? pos : neg;
        const int jj0 = is_pos ? i0 : i0 - EP;
        float t[8];
#pragma unroll
        for (int k = 0; k < 8; ++k) {
            const int e0 = eptr[jj0 + k];
            const int e1 = eptr[EP + jj0 + k];
            ushort4 uv = u16[(size_t)e0 * HD + lane];
            const unsigned short* __restrict__ dptr = zs16 + (size_t)e1 * HD + lane;
            float u0 = __uint_as_float((unsigned)uv.x << 16);
            float u1 = __uint_as_float((unsigned)uv.y << 16);
            float u2 = __uint_as_float((unsigned)uv.z << 16);
            float u3 = __uint_as_float((unsigned)uv.w << 16);
            float d0 = __uint_as_float((unsigned)dptr[0 * NH] << 16);
            float d1 = __uint_as_float((unsigned)dptr[1 * NH] << 16);
            float d2 = __uint_as_float((unsigned)dptr[2 * NH] << 16);
            float d3 = __uint_as_float((unsigned)dptr[3 * NH] << 16);
            float s = u0 * d0;
            s = fmaf(u1, d1, s);
            s = fmaf(u2, d2, s);
            s = fmaf(u3, d3, s);
            t[k] = s;
        }
#pragma unroll
        for (int st = 1; st <= 32; st <<= 1) {
#pragma unroll
            for (int k = 0; k < 8; ++k) t[k] += __shfl_xor(t[k], st);
        }
        if (lane < 8) {
            float tt = t[0];
            tt = (lane == 1) ? t[1] : tt;
            tt = (lane == 2) ? t[2] : tt;
            tt = (lane == 3) ? t[3] : tt;
            tt = (lane == 4) ? t[4] : tt;
            tt = (lane == 5) ? t[5] : tt;
            tt = (lane == 6) ? t[6] : tt;
            tt = (lane == 7) ? t[7] : tt;
            float logit  = tt + bpv;
            float target = (i0 + lane == EP) ? 1.f : 0.f;
            lsum += fmaxf(logit, 0.f) - logit * target + log1pf(expf(-fabsf(logit)));
        }
    }
#pragma unroll
    for (int off = 32; off >= 1; off >>= 1) lsum += __shfl_xor(lsum, off);
    __shared__ float wsum[4];
    if (lane == 0) wsum[wid] = lsum;
    __syncthreads();
    if (threadIdx.x == 0) {
        double bs = (double)wsum[0] + (double)wsum[1] + (double)wsum[2] + (double)wsum[3];
        atomicAdd(acc, bs);
    }
}

__global__ void loss_final(const double* __restrict__ acc, float* __restrict__ out, int denom) {
    out[0] = (float)(acc[0] / (double)denom);
}

extern "C" void kernel_launch(void* const* d_in, const int* in_sizes, int n_in,
                              void* d_out, int out_size, void* d_ws, size_t ws_size,
                              hipStream_t stream) {
    const float* x   = (const float*)d_in[0];
    const int*   ei  = (const int*)d_in[1];
    const int*   pos = (const int*)d_in[2];
    const int*   neg = (const int*)d_in[3];
    const float* W0  = (const float*)d_in[4];
    const float* b0  = (const float*)d_in[5];
    const float* Wh  = (const float*)d_in[6];
    const float* bh  = (const float*)d_in[7];
    const float* Wp  = (const float*)d_in[8];
    const float* bp  = (const float*)d_in[9];
    const int E  = in_sizes[1] / 2;   // 800000
    const int EP = in_sizes[2] / 2;   // 100000
    const int N  = N_NODES;

    // ---- workspace layout (256B aligned) ----
    char* ws = (char*)d_ws;
    size_t off_b = 0;
    auto alloc = [&](size_t bytes) { char* p = ws + off_b; off_b = (off_b + bytes + 255) & ~(size_t)255; return p; };
    float* zs = (float*)alloc((size_t)4 * N * HD * sizeof(float));           // 51.2 MB
    char*  hw_u = alloc((size_t)N * HD * sizeof(ushort4));                   // 25.6 MB (hw / u16 union)
    float*   hw  = (float*)hw_u;
    ushort4* u16 = (ushort4*)hw_u;
    __hip_bfloat16* zs16 = (__hip_bfloat16*)alloc((size_t)4 * N * HD * sizeof(__hip_bfloat16)); // 25.6 MB
    float* dis = (float*)alloc((size_t)N * sizeof(float));                   // 200 KB
    int*   off = (int*)alloc((size_t)(N + 1) * sizeof(int));                 // 200 KB
    int*   csr = (int*)alloc((size_t)E * sizeof(int));                       // 3.2 MB
    char*  zbase = ws + off_b;
    int*   cnt = (int*)alloc((size_t)N * sizeof(int));                       // 200 KB
    int*   cur = (int*)alloc((size_t)N * sizeof(int));                       // 200 KB
    double* acc = (double*)alloc(sizeof(double));
    size_t zero_bytes = (size_t)((char*)acc - zbase) + sizeof(double);

    hipMemsetAsync(zbase, 0, zero_bytes, stream);

    const int* src = ei;
    const int* dst = ei + E;

    // CSR build: histogram -> scan -> fill; dis from histogram
    hist_kernel<<<(E + 255) / 256, 256, 0, stream>>>(dst, cnt, E);
    scan_kernel<<<1, 256, 0, stream>>>(cnt, off, N);
    dis_kernel<<<(N + 255) / 256, 256, 0, stream>>>(cnt, dis, N);
    fill_kernel<<<(E + 255) / 256, 256, 0, stream>>>(src, dst, off, cur, csr, E);

    const int agg_blocks  = (N + 3) / 4;
    const int gemm_blocks = (N + 63) / 64;

    // layer 0
    gemm_kernel<128><<<gemm_blocks, 256, 0, stream>>>(x, W0, hw, N);
    agg_kernel<<<agg_blocks, 256, 0, stream>>>(csr, off, dis, hw, b0, zs, zs16, N);

    // layers 1..3
    for (int l = 1; l < 4; ++l) {
        float* zprev = zs + (size_t)(l - 1) * N * HD;
        float* zcur  = zs + (size_t)l * N * HD;
        __hip_bfloat16* zcur16 = zs16 + (size_t)l * N * HD;
        gemm_kernel<64><<<gemm_blocks, 256, 0, stream>>>(zprev, Wh + (size_t)(l - 1) * HD * HD, hw, N);
        agg_kernel<<<agg_blocks, 256, 0, stream>>>(csr, off, dis, hw,
                                                   bh + (size_t)(l - 1) * HD, zcur, zcur16, N);
    }

    // link prediction + loss
    uprep_kernel<<<(N * HD + 255) / 256, 256, 0, stream>>>(zs16, Wp, u16, N);
    linkpred_kernel<<<2048, 256, 0, stream>>>(u16, (const unsigned short*)zs16,
                                              pos, neg, bp, acc, EP);
    loss_final<<<1, 1, 0, stream>>>(acc, (float*)d_out, 2 * EP);
}

// Round 8
// 377.211 us; speedup vs baseline: 1.5386x; 1.5386x over previous
//
#include <hip/hip_runtime.h>
#include <hip/hip_bf16.h>
#include <math.h>

constexpr int N_NODES = 50000;
constexpr int HD = 64;

// ---------- histogram: cnt[d]++ ----------
__global__ __launch_bounds__(256) void hist_kernel(const int* __restrict__ dst,
                                                   int* __restrict__ cnt, int E) {
    int i = blockIdx.x * blockDim.x + threadIdx.x;
    if (i < E) atomicAdd(&cnt[dst[i]], 1);
}

// ---------- hierarchical exclusive scan: block-local ----------
__global__ __launch_bounds__(256) void scan1_kernel(const int* __restrict__ cnt,
                                                    int* __restrict__ off,
                                                    int* __restrict__ bsum, int N) {
    const int t = threadIdx.x;
    const int i = blockIdx.x * 256 + t;
    const int v = (i < N) ? cnt[i] : 0;
    const int lane = t & 63, wid = t >> 6;
    int incl = v;
#pragma unroll
    for (int o = 1; o <= 32; o <<= 1) {
        int u = __shfl_up(incl, o);
        if (lane >= o) incl += u;
    }
    __shared__ int wt[4];
    if (lane == 63) wt[wid] = incl;
    __syncthreads();
    int base = 0;
    for (int w = 0; w < wid; ++w) base += wt[w];
    if (i < N) off[i] = base + incl - v;
    if (t == 255) bsum[blockIdx.x] = base + incl;
}

// ---------- scan of block sums (NB <= 256), in-place exclusive ----------
__global__ __launch_bounds__(256) void scan2_kernel(int* __restrict__ bsum, int NB) {
    const int t = threadIdx.x;
    const int v = (t < NB) ? bsum[t] : 0;
    const int lane = t & 63, wid = t >> 6;
    int incl = v;
#pragma unroll
    for (int o = 1; o <= 32; o <<= 1) {
        int u = __shfl_up(incl, o);
        if (lane >= o) incl += u;
    }
    __shared__ int wt[4];
    if (lane == 63) wt[wid] = incl;
    __syncthreads();
    int base = 0;
    for (int w = 0; w < wid; ++w) base += wt[w];
    if (t < NB) bsum[t] = base + incl - v;
}

// ---------- add block offsets; write off[N] ----------
__global__ __launch_bounds__(256) void scan3_kernel(int* __restrict__ off,
                                                    const int* __restrict__ bsum,
                                                    const int* __restrict__ cnt, int N) {
    const int i = blockIdx.x * 256 + threadIdx.x;
    if (i < N) {
        int o = off[i] + bsum[blockIdx.x];
        off[i] = o;
        if (i == N - 1) off[N] = o + cnt[i];
    }
}

__global__ __launch_bounds__(256) void dis_kernel(const int* __restrict__ cnt,
                                                  float* __restrict__ dis, int N) {
    int i = blockIdx.x * blockDim.x + threadIdx.x;
    if (i < N) dis[i] = rsqrtf((float)cnt[i] + 1.0f);
}

// ---------- CSR fill ----------
__global__ __launch_bounds__(256) void fill_kernel(const int* __restrict__ src,
                                                   const int* __restrict__ dst,
                                                   const int* __restrict__ off,
                                                   int* __restrict__ cur,
                                                   int* __restrict__ csr, int E) {
    int i = blockIdx.x * blockDim.x + threadIdx.x;
    if (i < E) {
        int d = dst[i];
        int slot = atomicAdd(&cur[d], 1);
        csr[off[d] + slot] = src[i];
    }
}

// ---------- GEMM: classic LDS-tiled, 64x64 block, 4x4 micro-tile ----------
template <int K>
__global__ __launch_bounds__(256) void gemm_kernel(const float* __restrict__ in,
                                                   const float* __restrict__ W,
                                                   float* __restrict__ out, int N) {
    __shared__ float xs[64][68];   // pad 68: b128 16B-aligned, broadcast reads conflict-free
    __shared__ float Wl[64][64];
    const int t = threadIdx.x;
    const int row0 = blockIdx.x * 64;
    const int cq = t & 15, rq = t >> 4;
    float acc[4][4] = {{0.f}};
    for (int kc = 0; kc < K; kc += 64) {
#pragma unroll
        for (int it = 0; it < 4; ++it) {
            const int idx = it * 256 + t;          // 0..1023
            const int r = idx >> 4, c4 = idx & 15;
            const int rr = min(row0 + r, N - 1);
            *(float4*)(&xs[r][c4 * 4]) = *(const float4*)(in + (size_t)rr * K + kc + c4 * 4);
            *(float4*)(&Wl[r][c4 * 4]) = *(const float4*)(W + (size_t)(kc + r) * HD + c4 * 4);
        }
        __syncthreads();
#pragma unroll
        for (int k4 = 0; k4 < 16; ++k4) {
            float a[4][4], b[4][4];
#pragma unroll
            for (int i = 0; i < 4; ++i)
                *(float4*)a[i] = *(const float4*)(&xs[rq * 4 + i][k4 * 4]);
#pragma unroll
            for (int kk = 0; kk < 4; ++kk)
                *(float4*)b[kk] = *(const float4*)(&Wl[k4 * 4 + kk][cq * 4]);
#pragma unroll
            for (int kk = 0; kk < 4; ++kk)
#pragma unroll
                for (int i = 0; i < 4; ++i)
#pragma unroll
                    for (int j = 0; j < 4; ++j)
                        acc[i][j] = fmaf(a[i][kk], b[kk][j], acc[i][j]);
        }
        __syncthreads();
    }
#pragma unroll
    for (int i = 0; i < 4; ++i) {
        const int r = row0 + rq * 4 + i;
        if (r < N)
            *(float4*)(out + (size_t)r * HD + cq * 4) =
                make_float4(acc[i][0], acc[i][1], acc[i][2], acc[i][3]);
    }
}

// ---------- fused aggregation, 4-edge-wide float4 gathers (CSR) ----------
__global__ __launch_bounds__(256) void agg_kernel(const int* __restrict__ csr,
                                                  const int* __restrict__ off,
                                                  const float* __restrict__ dis,
                                                  const float* __restrict__ hw,
                                                  const float* __restrict__ b,
                                                  float* __restrict__ out,
                                                  __hip_bfloat16* __restrict__ out16, int N) {
    const int lane = threadIdx.x & 63;
    const int wid  = threadIdx.x >> 6;
    const int n = blockIdx.x * 4 + wid;
    if (n >= N) return;
    const int beg = off[n];
    const int c = min(off[n + 1] - beg, 64);
    int   s_l = 0;
    float w_l = 0.f;
    if (lane < c) {
        s_l = csr[beg + lane];
        w_l = dis[s_l];
    }
    const float dn = dis[n];
    const int g = lane >> 4;
    const int p = lane & 15;
    float ax = 0.f, ay = 0.f, az = 0.f, aw = 0.f;
    for (int e = 0; e < c; e += 4) {
        const int   ee = e + g;
        const int   sE = __shfl(s_l, ee);
        const float wE = __shfl(w_l, ee);
        const float4 hv = *(const float4*)(hw + (size_t)sE * HD + p * 4);
        ax = fmaf(hv.x, wE, ax);
        ay = fmaf(hv.y, wE, ay);
        az = fmaf(hv.z, wE, az);
        aw = fmaf(hv.w, wE, aw);
    }
#pragma unroll
    for (int st = 16; st <= 32; st <<= 1) {
        ax += __shfl_xor(ax, st);
        ay += __shfl_xor(ay, st);
        az += __shfl_xor(az, st);
        aw += __shfl_xor(aw, st);
    }
    if (g == 0) {
        const float4 self = *(const float4*)(hw + (size_t)n * HD + p * 4);
        const float4 bv   = *(const float4*)(b + p * 4);
        float4 v;
        v.x = fmaxf(fmaf(ax + self.x * dn, dn, bv.x), 0.f);
        v.y = fmaxf(fmaf(ay + self.y * dn, dn, bv.y), 0.f);
        v.z = fmaxf(fmaf(az + self.z * dn, dn, bv.z), 0.f);
        v.w = fmaxf(fmaf(aw + self.w * dn, dn, bv.w), 0.f);
        *(float4*)(out + (size_t)n * HD + p * 4) = v;
        ushort4 o16;
        __hip_bfloat16 t0 = __float2bfloat16(v.x);
        __hip_bfloat16 t1 = __float2bfloat16(v.y);
        __hip_bfloat16 t2 = __float2bfloat16(v.z);
        __hip_bfloat16 t3 = __float2bfloat16(v.w);
        o16.x = *(unsigned short*)&t0;
        o16.y = *(unsigned short*)&t1;
        o16.z = *(unsigned short*)&t2;
        o16.w = *(unsigned short*)&t3;
        *(ushort4*)((unsigned short*)out16 + (size_t)n * HD + p * 4) = o16;
    }
}

// ---------- u-precompute ----------
__global__ __launch_bounds__(256) void uprep_kernel(const __hip_bfloat16* __restrict__ zs16,
                                                    const float* __restrict__ Wp,
                                                    ushort4* __restrict__ u16, int N) {
    const int i = blockIdx.x * blockDim.x + threadIdx.x;
    const int total = N * HD;
    if (i >= total) return;
    const size_t NH = (size_t)N_NODES * HD;
    float z0 = __bfloat162float(zs16[0 * NH + i]);
    float z1 = __bfloat162float(zs16[1 * NH + i]);
    float z2 = __bfloat162float(zs16[2 * NH + i]);
    float z3 = __bfloat162float(zs16[3 * NH + i]);
    ushort4 r;
    unsigned short* rp = (unsigned short*)&r;
#pragma unroll
    for (int m = 0; m < 4; ++m) {
        float um = z0 * Wp[0 * 4 + m] + z1 * Wp[1 * 4 + m] + z2 * Wp[2 * 4 + m] + z3 * Wp[3 * 4 + m];
        __hip_bfloat16 bv = __float2bfloat16(um);
        rp[m] = *(unsigned short*)&bv;
    }
    u16[i] = r;
}

// ---------- link prediction + BCE loss: 8 edges per wave-iteration ----------
__global__ __launch_bounds__(256) void linkpred_kernel(const ushort4* __restrict__ u16,
                                                       const unsigned short* __restrict__ zs16,
                                                       const int* __restrict__ pos,
                                                       const int* __restrict__ neg,
                                                       const float* __restrict__ bp,
                                                       double* __restrict__ acc, int EP) {
    const int lane = threadIdx.x & 63;
    const int wid  = threadIdx.x >> 6;
    const size_t NH = (size_t)N_NODES * HD;
    const float bpv = bp[0];
    int gw = blockIdx.x * 4 + wid;
    const int nw = gridDim.x * 4;
    const int nchunks = (2 * EP) >> 3;
    float lsum = 0.f;
    for (int c0 = gw; c0 < nchunks; c0 += nw) {
        const int c = __builtin_amdgcn_readfirstlane(c0);
        const int i0 = c << 3;
        const bool is_pos = i0 < EP;
        const int* __restrict__ eptr = is_pos ? pos : neg;
        const int jj0 = is_pos ? i0 : i0 - EP;
        float t[8];
#pragma unroll
        for (int k = 0; k < 8; ++k) {
            const int e0 = eptr[jj0 + k];
            const int e1 = eptr[EP + jj0 + k];
            ushort4 uv = u16[(size_t)e0 * HD + lane];
            const unsigned short* __restrict__ dptr = zs16 + (size_t)e1 * HD + lane;
            float u0 = __uint_as_float((unsigned)uv.x << 16);
            float u1 = __uint_as_float((unsigned)uv.y << 16);
            float u2 = __uint_as_float((unsigned)uv.z << 16);
            float u3 = __uint_as_float((unsigned)uv.w << 16);
            float d0 = __uint_as_float((unsigned)dptr[0 * NH] << 16);
            float d1 = __uint_as_float((unsigned)dptr[1 * NH] << 16);
            float d2 = __uint_as_float((unsigned)dptr[2 * NH] << 16);
            float d3 = __uint_as_float((unsigned)dptr[3 * NH] << 16);
            float s = u0 * d0;
            s = fmaf(u1, d1, s);
            s = fmaf(u2, d2, s);
            s = fmaf(u3, d3, s);
            t[k] = s;
        }
#pragma unroll
        for (int st = 1; st <= 32; st <<= 1) {
#pragma unroll
            for (int k = 0; k < 8; ++k) t[k] += __shfl_xor(t[k], st);
        }
        if (lane < 8) {
            float tt = t[0];
            tt = (lane == 1) ? t[1] : tt;
            tt = (lane == 2) ? t[2] : tt;
            tt = (lane == 3) ? t[3] : tt;
            tt = (lane == 4) ? t[4] : tt;
            tt = (lane == 5) ? t[5] : tt;
            tt = (lane == 6) ? t[6] : tt;
            tt = (lane == 7) ? t[7] : tt;
            float logit  = tt + bpv;
            float target = (i0 + lane == EP) ? 1.f : 0.f;
            lsum += fmaxf(logit, 0.f) - logit * target + log1pf(expf(-fabsf(logit)));
        }
    }
#pragma unroll
    for (int off = 32; off >= 1; off >>= 1) lsum += __shfl_xor(lsum, off);
    __shared__ float wsum[4];
    if (lane == 0) wsum[wid] = lsum;
    __syncthreads();
    if (threadIdx.x == 0) {
        double bs = (double)wsum[0] + (double)wsum[1] + (double)wsum[2] + (double)wsum[3];
        atomicAdd(acc, bs);
    }
}

__global__ void loss_final(const double* __restrict__ acc, float* __restrict__ out, int denom) {
    out[0] = (float)(acc[0] / (double)denom);
}

extern "C" void kernel_launch(void* const* d_in, const int* in_sizes, int n_in,
                              void* d_out, int out_size, void* d_ws, size_t ws_size,
                              hipStream_t stream) {
    const float* x   = (const float*)d_in[0];
    const int*   ei  = (const int*)d_in[1];
    const int*   pos = (const int*)d_in[2];
    const int*   neg = (const int*)d_in[3];
    const float* W0  = (const float*)d_in[4];
    const float* b0  = (const float*)d_in[5];
    const float* Wh  = (const float*)d_in[6];
    const float* bh  = (const float*)d_in[7];
    const float* Wp  = (const float*)d_in[8];
    const float* bp  = (const float*)d_in[9];
    const int E  = in_sizes[1] / 2;   // 800000
    const int EP = in_sizes[2] / 2;   // 100000
    const int N  = N_NODES;

    // ---- workspace layout (256B aligned) ----
    char* ws = (char*)d_ws;
    size_t off_b = 0;
    auto alloc = [&](size_t bytes) { char* p = ws + off_b; off_b = (off_b + bytes + 255) & ~(size_t)255; return p; };
    float* zs = (float*)alloc((size_t)4 * N * HD * sizeof(float));           // 51.2 MB
    char*  hw_u = alloc((size_t)N * HD * sizeof(ushort4));                   // 25.6 MB (hw / u16 union)
    float*   hw  = (float*)hw_u;
    ushort4* u16 = (ushort4*)hw_u;
    __hip_bfloat16* zs16 = (__hip_bfloat16*)alloc((size_t)4 * N * HD * sizeof(__hip_bfloat16)); // 25.6 MB
    float* dis = (float*)alloc((size_t)N * sizeof(float));                   // 200 KB
    int*   off = (int*)alloc((size_t)(N + 1) * sizeof(int));                 // 200 KB
    int*   csr = (int*)alloc((size_t)E * sizeof(int));                       // 3.2 MB
    int*   bsum = (int*)alloc((size_t)256 * sizeof(int));                    // 1 KB
    char*  zbase = ws + off_b;
    int*   cnt = (int*)alloc((size_t)N * sizeof(int));                       // 200 KB
    int*   cur = (int*)alloc((size_t)N * sizeof(int));                       // 200 KB
    double* acc = (double*)alloc(sizeof(double));
    size_t zero_bytes = (size_t)((char*)acc - zbase) + sizeof(double);

    hipMemsetAsync(zbase, 0, zero_bytes, stream);

    const int* src = ei;
    const int* dst = ei + E;

    const int NB = (N + 255) / 256;    // 196 scan blocks
    hist_kernel<<<(E + 255) / 256, 256, 0, stream>>>(dst, cnt, E);
    scan1_kernel<<<NB, 256, 0, stream>>>(cnt, off, bsum, N);
    scan2_kernel<<<1, 256, 0, stream>>>(bsum, NB);
    scan3_kernel<<<NB, 256, 0, stream>>>(off, bsum, cnt, N);
    dis_kernel<<<(N + 255) / 256, 256, 0, stream>>>(cnt, dis, N);
    fill_kernel<<<(E + 255) / 256, 256, 0, stream>>>(src, dst, off, cur, csr, E);

    const int agg_blocks  = (N + 3) / 4;
    const int gemm_blocks = (N + 63) / 64;

    // layer 0
    gemm_kernel<128><<<gemm_blocks, 256, 0, stream>>>(x, W0, hw, N);
    agg_kernel<<<agg_blocks, 256, 0, stream>>>(csr, off, dis, hw, b0, zs, zs16, N);

    // layers 1..3
    for (int l = 1; l < 4; ++l) {
        float* zprev = zs + (size_t)(l - 1) * N * HD;
        float* zcur  = zs + (size_t)l * N * HD;
        __hip_bfloat16* zcur16 = zs16 + (size_t)l * N * HD;
        gemm_kernel<64><<<gemm_blocks, 256, 0, stream>>>(zprev, Wh + (size_t)(l - 1) * HD * HD, hw, N);
        agg_kernel<<<agg_blocks, 256, 0, stream>>>(csr, off, dis, hw,
                                                   bh + (size_t)(l - 1) * HD, zcur, zcur16, N);
    }

    // link prediction + loss
    uprep_kernel<<<(N * HD + 255) / 256, 256, 0, stream>>>(zs16, Wp, u16, N);
    linkpred_kernel<<<2048, 256, 0, stream>>>(u16, (const unsigned short*)zs16,
                                              pos, neg, bp, acc, EP);
    loss_final<<<1, 1, 0, stream>>>(acc, (float*)d_out, 2 * EP);
}

// Round 9
// 306.056 us; speedup vs baseline: 1.8963x; 1.2325x over previous
//
#include <hip/hip_runtime.h>
#include <hip/hip_bf16.h>
#include <math.h>

constexpr int N_NODES = 50000;
constexpr int HD = 64;
constexpr int NBKT = (N_NODES + 255) / 256;   // 196 buckets of 256 nodes

// ---------- A: bucket histogram (LDS-staged) ----------
__global__ __launch_bounds__(256) void bhist_kernel(const int* __restrict__ dst,
                                                    int* __restrict__ bcnt, int E) {
    __shared__ int lh[256];
    const int t = threadIdx.x;
    lh[t] = 0;
    __syncthreads();
    const int beg = blockIdx.x * 2048;
    const int end = min(beg + 2048, E);
    for (int i = beg + t; i < end; i += 256)
        atomicAdd(&lh[dst[i] >> 8], 1);
    __syncthreads();
    if (t < NBKT && lh[t]) atomicAdd(&bcnt[t], lh[t]);
}

// ---------- B: scan bucket counts -> bbase, init gcur ----------
__global__ __launch_bounds__(256) void bscan_kernel(const int* __restrict__ bcnt,
                                                    int* __restrict__ bbase,
                                                    int* __restrict__ gcur) {
    const int t = threadIdx.x;
    const int v = (t < NBKT) ? bcnt[t] : 0;
    const int lane = t & 63, wid = t >> 6;
    int incl = v;
#pragma unroll
    for (int o = 1; o <= 32; o <<= 1) {
        int u = __shfl_up(incl, o);
        if (lane >= o) incl += u;
    }
    __shared__ int wt[4];
    if (lane == 63) wt[wid] = incl;
    __syncthreads();
    int base = 0;
    for (int w = 0; w < wid; ++w) base += wt[w];
    const int excl = base + incl - v;
    if (t < NBKT) { bbase[t] = excl; gcur[t] = excl; }
    if (t == NBKT - 1) bbase[NBKT] = excl + v;
}

// ---------- C: partition edges into bucket-grouped pk (coalesced-run writes) ----------
__global__ __launch_bounds__(256) void partition_kernel(const int* __restrict__ src,
                                                        const int* __restrict__ dst,
                                                        int* __restrict__ gcur,
                                                        unsigned* __restrict__ pk, int E) {
    __shared__ unsigned epk[8192];
    __shared__ int lh[NBKT], lbase[NBKT], lcur[NBKT];
    const int t = threadIdx.x;
    for (int i = t; i < NBKT; i += 256) { lh[i] = 0; lcur[i] = 0; }
    __syncthreads();
    const int beg = blockIdx.x * 8192;
    const int end = min(beg + 8192, E);
    for (int i = beg + t; i < end; i += 256) {
        const int s = src[i], d = dst[i];
        const int bkt = d >> 8;
        epk[i - beg] = ((unsigned)bkt << 24) | ((unsigned)(d & 255) << 16) | (unsigned)s;
        atomicAdd(&lh[bkt], 1);
    }
    __syncthreads();
    for (int i = t; i < NBKT; i += 256)
        if (lh[i]) lbase[i] = atomicAdd(&gcur[i], lh[i]);
    __syncthreads();
    for (int i = beg + t; i < end; i += 256) {
        const unsigned p = epk[i - beg];
        const int bkt = p >> 24;
        const int r = atomicAdd(&lcur[bkt], 1);
        pk[lbase[bkt] + r] = p;
    }
}

// ---------- D: per-bucket counting sort -> csr, off, dis ----------
__global__ __launch_bounds__(256) void bsort_kernel(const unsigned* __restrict__ pk,
                                                    const int* __restrict__ bbase,
                                                    int* __restrict__ off,
                                                    float* __restrict__ dis,
                                                    int* __restrict__ csr, int E, int N) {
    __shared__ int ncnt[256], nbs[256], ncur[256];
    __shared__ int wt[4];
    const int t = threadIdx.x;
    const int bkt = blockIdx.x;
    const int gb = bbase[bkt], ge = bbase[bkt + 1];
    ncnt[t] = 0; ncur[t] = 0;
    __syncthreads();
    for (int i = gb + t; i < ge; i += 256)
        atomicAdd(&ncnt[(pk[i] >> 16) & 255], 1);
    __syncthreads();
    const int v = ncnt[t];
    const int lane = t & 63, wid = t >> 6;
    int incl = v;
#pragma unroll
    for (int o = 1; o <= 32; o <<= 1) {
        int u = __shfl_up(incl, o);
        if (lane >= o) incl += u;
    }
    if (lane == 63) wt[wid] = incl;
    __syncthreads();
    int base = 0;
    for (int w = 0; w < wid; ++w) base += wt[w];
    nbs[t] = base + incl - v;   // exclusive prefix within bucket
    const int n = bkt * 256 + t;
    if (n < N) {
        off[n] = gb + nbs[t];
        dis[n] = rsqrtf((float)v + 1.0f);
        if (n == N - 1) off[N] = E;
    }
    __syncthreads();
    for (int i = gb + t; i < ge; i += 256) {
        const unsigned p = pk[i];
        const int dl = (p >> 16) & 255;
        const int r = atomicAdd(&ncur[dl], 1);
        csr[gb + nbs[dl] + r] = (int)(p & 0xFFFFu);
    }
}

// ---------- GEMM: LDS-tiled 64x64, 4x4 micro-tile; writes fp32 + bf16 mirror ----------
template <int K>
__global__ __launch_bounds__(256) void gemm_kernel(const float* __restrict__ in,
                                                   const float* __restrict__ W,
                                                   float* __restrict__ out,
                                                   unsigned short* __restrict__ out16, int N) {
    __shared__ float xs[64][68];
    __shared__ float Wl[64][64];
    const int t = threadIdx.x;
    const int row0 = blockIdx.x * 64;
    const int cq = t & 15, rq = t >> 4;
    float acc[4][4] = {{0.f}};
    for (int kc = 0; kc < K; kc += 64) {
#pragma unroll
        for (int it = 0; it < 4; ++it) {
            const int idx = it * 256 + t;
            const int r = idx >> 4, c4 = idx & 15;
            const int rr = min(row0 + r, N - 1);
            *(float4*)(&xs[r][c4 * 4]) = *(const float4*)(in + (size_t)rr * K + kc + c4 * 4);
            *(float4*)(&Wl[r][c4 * 4]) = *(const float4*)(W + (size_t)(kc + r) * HD + c4 * 4);
        }
        __syncthreads();
#pragma unroll
        for (int k4 = 0; k4 < 16; ++k4) {
            float a[4][4], b[4][4];
#pragma unroll
            for (int i = 0; i < 4; ++i)
                *(float4*)a[i] = *(const float4*)(&xs[rq * 4 + i][k4 * 4]);
#pragma unroll
            for (int kk = 0; kk < 4; ++kk)
                *(float4*)b[kk] = *(const float4*)(&Wl[k4 * 4 + kk][cq * 4]);
#pragma unroll
            for (int kk = 0; kk < 4; ++kk)
#pragma unroll
                for (int i = 0; i < 4; ++i)
#pragma unroll
                    for (int j = 0; j < 4; ++j)
                        acc[i][j] = fmaf(a[i][kk], b[kk][j], acc[i][j]);
        }
        __syncthreads();
    }
#pragma unroll
    for (int i = 0; i < 4; ++i) {
        const int r = row0 + rq * 4 + i;
        if (r < N) {
            *(float4*)(out + (size_t)r * HD + cq * 4) =
                make_float4(acc[i][0], acc[i][1], acc[i][2], acc[i][3]);
            ushort4 o16;
            __hip_bfloat16 b0 = __float2bfloat16(acc[i][0]);
            __hip_bfloat16 b1 = __float2bfloat16(acc[i][1]);
            __hip_bfloat16 b2 = __float2bfloat16(acc[i][2]);
            __hip_bfloat16 b3 = __float2bfloat16(acc[i][3]);
            o16.x = *(unsigned short*)&b0; o16.y = *(unsigned short*)&b1;
            o16.z = *(unsigned short*)&b2; o16.w = *(unsigned short*)&b3;
            *(ushort4*)(out16 + (size_t)r * HD + cq * 4) = o16;
        }
    }
}

// ---------- fused aggregation: bf16 neighbor gathers, fp32 self/output ----------
__global__ __launch_bounds__(256) void agg_kernel(const int* __restrict__ csr,
                                                  const int* __restrict__ off,
                                                  const float* __restrict__ dis,
                                                  const float* __restrict__ hw,
                                                  const unsigned short* __restrict__ hw16,
                                                  const float* __restrict__ b,
                                                  float* __restrict__ out,
                                                  __hip_bfloat16* __restrict__ out16, int N) {
    const int lane = threadIdx.x & 63;
    const int wid  = threadIdx.x >> 6;
    const int n = blockIdx.x * 4 + wid;
    if (n >= N) return;
    const int beg = off[n];
    const int c = min(off[n + 1] - beg, 64);
    int   s_l = 0;
    float w_l = 0.f;
    if (lane < c) {
        s_l = csr[beg + lane];
        w_l = dis[s_l];
    }
    const float dn = dis[n];
    const int g = lane >> 4;
    const int p = lane & 15;
    float ax = 0.f, ay = 0.f, az = 0.f, aw = 0.f;
    for (int e = 0; e < c; e += 4) {
        const int   ee = e + g;
        const int   sE = __shfl(s_l, ee);
        const float wE = __shfl(w_l, ee);
        const ushort4 hv = *(const ushort4*)(hw16 + (size_t)sE * HD + p * 4);
        ax = fmaf(__uint_as_float((unsigned)hv.x << 16), wE, ax);
        ay = fmaf(__uint_as_float((unsigned)hv.y << 16), wE, ay);
        az = fmaf(__uint_as_float((unsigned)hv.z << 16), wE, az);
        aw = fmaf(__uint_as_float((unsigned)hv.w << 16), wE, aw);
    }
#pragma unroll
    for (int st = 16; st <= 32; st <<= 1) {
        ax += __shfl_xor(ax, st);
        ay += __shfl_xor(ay, st);
        az += __shfl_xor(az, st);
        aw += __shfl_xor(aw, st);
    }
    if (g == 0) {
        const float4 self = *(const float4*)(hw + (size_t)n * HD + p * 4);
        const float4 bv   = *(const float4*)(b + p * 4);
        float4 v;
        v.x = fmaxf(fmaf(ax + self.x * dn, dn, bv.x), 0.f);
        v.y = fmaxf(fmaf(ay + self.y * dn, dn, bv.y), 0.f);
        v.z = fmaxf(fmaf(az + self.z * dn, dn, bv.z), 0.f);
        v.w = fmaxf(fmaf(aw + self.w * dn, dn, bv.w), 0.f);
        *(float4*)(out + (size_t)n * HD + p * 4) = v;
        ushort4 o16;
        __hip_bfloat16 t0 = __float2bfloat16(v.x);
        __hip_bfloat16 t1 = __float2bfloat16(v.y);
        __hip_bfloat16 t2 = __float2bfloat16(v.z);
        __hip_bfloat16 t3 = __float2bfloat16(v.w);
        o16.x = *(unsigned short*)&t0;
        o16.y = *(unsigned short*)&t1;
        o16.z = *(unsigned short*)&t2;
        o16.w = *(unsigned short*)&t3;
        *(ushort4*)((unsigned short*)out16 + (size_t)n * HD + p * 4) = o16;
    }
}

// ---------- u-precompute ----------
__global__ __launch_bounds__(256) void uprep_kernel(const __hip_bfloat16* __restrict__ zs16,
                                                    const float* __restrict__ Wp,
                                                    ushort4* __restrict__ u16, int N) {
    const int i = blockIdx.x * blockDim.x + threadIdx.x;
    const int total = N * HD;
    if (i >= total) return;
    const size_t NH = (size_t)N_NODES * HD;
    float z0 = __bfloat162float(zs16[0 * NH + i]);
    float z1 = __bfloat162float(zs16[1 * NH + i]);
    float z2 = __bfloat162float(zs16[2 * NH + i]);
    float z3 = __bfloat162float(zs16[3 * NH + i]);
    ushort4 r;
    unsigned short* rp = (unsigned short*)&r;
#pragma unroll
    for (int m = 0; m < 4; ++m) {
        float um = z0 * Wp[0 * 4 + m] + z1 * Wp[1 * 4 + m] + z2 * Wp[2 * 4 + m] + z3 * Wp[3 * 4 + m];
        __hip_bfloat16 bv = __float2bfloat16(um);
        rp[m] = *(unsigned short*)&bv;
    }
    u16[i] = r;
}

// ---------- link prediction + BCE loss: 8 edges per wave-iteration ----------
__global__ __launch_bounds__(256) void linkpred_kernel(const ushort4* __restrict__ u16,
                                                       const unsigned short* __restrict__ zs16,
                                                       const int* __restrict__ pos,
                                                       const int* __restrict__ neg,
                                                       const float* __restrict__ bp,
                                                       double* __restrict__ acc, int EP) {
    const int lane = threadIdx.x & 63;
    const int wid  = threadIdx.x >> 6;
    const size_t NH = (size_t)N_NODES * HD;
    const float bpv = bp[0];
    int gw = blockIdx.x * 4 + wid;
    const int nw = gridDim.x * 4;
    const int nchunks = (2 * EP) >> 3;
    float lsum = 0.f;
    for (int c0 = gw; c0 < nchunks; c0 += nw) {
        const int c = __builtin_amdgcn_readfirstlane(c0);
        const int i0 = c << 3;
        const bool is_pos = i0 < EP;
        const int* __restrict__ eptr = is_pos ? pos : neg;
        const int jj0 = is_pos ? i0 : i0 - EP;
        float t[8];
#pragma unroll
        for (int k = 0; k < 8; ++k) {
            const int e0 = eptr[jj0 + k];
            const int e1 = eptr[EP + jj0 + k];
            ushort4 uv = u16[(size_t)e0 * HD + lane];
            const unsigned short* __restrict__ dptr = zs16 + (size_t)e1 * HD + lane;
            float u0 = __uint_as_float((unsigned)uv.x << 16);
            float u1 = __uint_as_float((unsigned)uv.y << 16);
            float u2 = __uint_as_float((unsigned)uv.z << 16);
            float u3 = __uint_as_float((unsigned)uv.w << 16);
            float d0 = __uint_as_float((unsigned)dptr[0 * NH] << 16);
            float d1 = __uint_as_float((unsigned)dptr[1 * NH] << 16);
            float d2 = __uint_as_float((unsigned)dptr[2 * NH] << 16);
            float d3 = __uint_as_float((unsigned)dptr[3 * NH] << 16);
            float s = u0 * d0;
            s = fmaf(u1, d1, s);
            s = fmaf(u2, d2, s);
            s = fmaf(u3, d3, s);
            t[k] = s;
        }
#pragma unroll
        for (int st = 1; st <= 32; st <<= 1) {
#pragma unroll
            for (int k = 0; k < 8; ++k) t[k] += __shfl_xor(t[k], st);
        }
        if (lane < 8) {
            float tt = t[0];
            tt = (lane == 1) ? t[1] : tt;
            tt = (lane == 2) ? t[2] : tt;
            tt = (lane == 3) ? t[3] : tt;
            tt = (lane == 4) ? t[4] : tt;
            tt = (lane == 5) ? t[5] : tt;
            tt = (lane == 6) ? t[6] : tt;
            tt = (lane == 7) ? t[7] : tt;
            float logit  = tt + bpv;
            float target = (i0 + lane == EP) ? 1.f : 0.f;
            lsum += fmaxf(logit, 0.f) - logit * target + log1pf(expf(-fabsf(logit)));
        }
    }
#pragma unroll
    for (int o = 32; o >= 1; o >>= 1) lsum += __shfl_xor(lsum, o);
    __shared__ float wsum[4];
    if (lane == 0) wsum[wid] = lsum;
    __syncthreads();
    if (threadIdx.x == 0) {
        double bs = (double)wsum[0] + (double)wsum[1] + (double)wsum[2] + (double)wsum[3];
        atomicAdd(acc, bs);
    }
}

__global__ void loss_final(const double* __restrict__ acc, float* __restrict__ out, int denom) {
    out[0] = (float)(acc[0] / (double)denom);
}

extern "C" void kernel_launch(void* const* d_in, const int* in_sizes, int n_in,
                              void* d_out, int out_size, void* d_ws, size_t ws_size,
                              hipStream_t stream) {
    const float* x   = (const float*)d_in[0];
    const int*   ei  = (const int*)d_in[1];
    const int*   pos = (const int*)d_in[2];
    const int*   neg = (const int*)d_in[3];
    const float* W0  = (const float*)d_in[4];
    const float* b0  = (const float*)d_in[5];
    const float* Wh  = (const float*)d_in[6];
    const float* bh  = (const float*)d_in[7];
    const float* Wp  = (const float*)d_in[8];
    const float* bp  = (const float*)d_in[9];
    const int E  = in_sizes[1] / 2;   // 800000
    const int EP = in_sizes[2] / 2;   // 100000
    const int N  = N_NODES;

    // ---- workspace layout (256B aligned) ----
    char* ws = (char*)d_ws;
    size_t off_b = 0;
    auto alloc = [&](size_t bytes) { char* p = ws + off_b; off_b = (off_b + bytes + 255) & ~(size_t)255; return p; };
    float* zs = (float*)alloc((size_t)4 * N * HD * sizeof(float));           // 51.2 MB
    char*  hw_u = alloc((size_t)N * HD * sizeof(ushort4));                   // 25.6 MB (hw fp32 / u16 union)
    float*   hw  = (float*)hw_u;
    ushort4* u16 = (ushort4*)hw_u;
    unsigned short* hw16 = (unsigned short*)alloc((size_t)N * HD * sizeof(unsigned short)); // 6.4 MB
    __hip_bfloat16* zs16 = (__hip_bfloat16*)alloc((size_t)4 * N * HD * sizeof(__hip_bfloat16)); // 25.6 MB
    float* dis = (float*)alloc((size_t)N * sizeof(float));                   // 200 KB
    int*   off = (int*)alloc((size_t)(N + 1) * sizeof(int));                 // 200 KB
    int*   csr = (int*)alloc((size_t)E * sizeof(int));                       // 3.2 MB
    unsigned* pk = (unsigned*)alloc((size_t)E * sizeof(unsigned));           // 3.2 MB
    int*   bbase = (int*)alloc((size_t)(NBKT + 1) * sizeof(int));
    int*   gcur  = (int*)alloc((size_t)NBKT * sizeof(int));
    char*  zbase = ws + off_b;
    int*   bcnt = (int*)alloc((size_t)NBKT * sizeof(int));
    double* acc = (double*)alloc(sizeof(double));
    size_t zero_bytes = (size_t)((char*)acc - zbase) + sizeof(double);

    hipMemsetAsync(zbase, 0, zero_bytes, stream);

    const int* src = ei;
    const int* dst = ei + E;

    // CSR build: bucket hist -> scan -> partition -> per-bucket sort (+off, dis)
    bhist_kernel<<<(E + 2047) / 2048, 256, 0, stream>>>(dst, bcnt, E);
    bscan_kernel<<<1, 256, 0, stream>>>(bcnt, bbase, gcur);
    partition_kernel<<<(E + 8191) / 8192, 256, 0, stream>>>(src, dst, gcur, pk, E);
    bsort_kernel<<<NBKT, 256, 0, stream>>>(pk, bbase, off, dis, csr, E, N);

    const int agg_blocks  = (N + 3) / 4;
    const int gemm_blocks = (N + 63) / 64;

    // layer 0
    gemm_kernel<128><<<gemm_blocks, 256, 0, stream>>>(x, W0, hw, hw16, N);
    agg_kernel<<<agg_blocks, 256, 0, stream>>>(csr, off, dis, hw, hw16, b0, zs, zs16, N);

    // layers 1..3
    for (int l = 1; l < 4; ++l) {
        float* zprev = zs + (size_t)(l - 1) * N * HD;
        float* zcur  = zs + (size_t)l * N * HD;
        __hip_bfloat16* zcur16 = zs16 + (size_t)l * N * HD;
        gemm_kernel<64><<<gemm_blocks, 256, 0, stream>>>(zprev, Wh + (size_t)(l - 1) * HD * HD, hw, hw16, N);
        agg_kernel<<<agg_blocks, 256, 0, stream>>>(csr, off, dis, hw, hw16,
                                                   bh + (size_t)(l - 1) * HD, zcur, zcur16, N);
    }

    // link prediction + loss
    uprep_kernel<<<(N * HD + 255) / 256, 256, 0, stream>>>(zs16, Wp, u16, N);
    linkpred_kernel<<<2048, 256, 0, stream>>>(u16, (const unsigned short*)zs16,
                                              pos, neg, bp, acc, EP);
    loss_final<<<1, 1, 0, stream>>>(acc, (float*)d_out, 2 * EP);
}

// Round 10
// 287.994 us; speedup vs baseline: 2.0152x; 1.0627x over previous
//
#include <hip/hip_runtime.h>
#include <hip/hip_bf16.h>
#include <math.h>

constexpr int N_NODES = 50000;
constexpr int HD = 64;
constexpr int NBKT = (N_NODES + 255) / 256;   // 196 buckets of 256 nodes

__device__ __forceinline__ float bf2f(unsigned short u) {
    return __uint_as_float((unsigned)u << 16);
}
__device__ __forceinline__ unsigned short f2bf(float f) {
    __hip_bfloat16 b = __float2bfloat16(f);
    return *(unsigned short*)&b;
}

// ---------- A: bucket histogram (LDS-staged) ----------
__global__ __launch_bounds__(256) void bhist_kernel(const int* __restrict__ dst,
                                                    int* __restrict__ bcnt, int E) {
    __shared__ int lh[256];
    const int t = threadIdx.x;
    lh[t] = 0;
    __syncthreads();
    const int beg = blockIdx.x * 2048;
    const int end = min(beg + 2048, E);
    for (int i = beg + t; i < end; i += 256)
        atomicAdd(&lh[dst[i] >> 8], 1);
    __syncthreads();
    if (t < NBKT && lh[t]) atomicAdd(&bcnt[t], lh[t]);
}

// ---------- B: scan bucket counts -> bbase, init gcur ----------
__global__ __launch_bounds__(256) void bscan_kernel(const int* __restrict__ bcnt,
                                                    int* __restrict__ bbase,
                                                    int* __restrict__ gcur) {
    const int t = threadIdx.x;
    const int v = (t < NBKT) ? bcnt[t] : 0;
    const int lane = t & 63, wid = t >> 6;
    int incl = v;
#pragma unroll
    for (int o = 1; o <= 32; o <<= 1) {
        int u = __shfl_up(incl, o);
        if (lane >= o) incl += u;
    }
    __shared__ int wt[4];
    if (lane == 63) wt[wid] = incl;
    __syncthreads();
    int base = 0;
    for (int w = 0; w < wid; ++w) base += wt[w];
    const int excl = base + incl - v;
    if (t < NBKT) { bbase[t] = excl; gcur[t] = excl; }
    if (t == NBKT - 1) bbase[NBKT] = excl + v;
}

// ---------- C: partition edges into bucket-grouped pk ----------
__global__ __launch_bounds__(256) void partition_kernel(const int* __restrict__ src,
                                                        const int* __restrict__ dst,
                                                        int* __restrict__ gcur,
                                                        unsigned* __restrict__ pk, int E) {
    __shared__ unsigned epk[8192];
    __shared__ int lh[NBKT], lbase[NBKT], lcur[NBKT];
    const int t = threadIdx.x;
    for (int i = t; i < NBKT; i += 256) { lh[i] = 0; lcur[i] = 0; }
    __syncthreads();
    const int beg = blockIdx.x * 8192;
    const int end = min(beg + 8192, E);
    for (int i = beg + t; i < end; i += 256) {
        const int s = src[i], d = dst[i];
        const int bkt = d >> 8;
        epk[i - beg] = ((unsigned)bkt << 24) | ((unsigned)(d & 255) << 16) | (unsigned)s;
        atomicAdd(&lh[bkt], 1);
    }
    __syncthreads();
    for (int i = t; i < NBKT; i += 256)
        if (lh[i]) lbase[i] = atomicAdd(&gcur[i], lh[i]);
    __syncthreads();
    for (int i = beg + t; i < end; i += 256) {
        const unsigned p = epk[i - beg];
        const int bkt = p >> 24;
        const int r = atomicAdd(&lcur[bkt], 1);
        pk[lbase[bkt] + r] = p;
    }
}

// ---------- D: per-bucket counting sort -> csr, off, dis ----------
__global__ __launch_bounds__(256) void bsort_kernel(const unsigned* __restrict__ pk,
                                                    const int* __restrict__ bbase,
                                                    int* __restrict__ off,
                                                    float* __restrict__ dis,
                                                    int* __restrict__ csr, int E, int N) {
    __shared__ int ncnt[256], nbs[256], ncur[256];
    __shared__ int wt[4];
    const int t = threadIdx.x;
    const int bkt = blockIdx.x;
    const int gb = bbase[bkt], ge = bbase[bkt + 1];
    ncnt[t] = 0; ncur[t] = 0;
    __syncthreads();
    for (int i = gb + t; i < ge; i += 256)
        atomicAdd(&ncnt[(pk[i] >> 16) & 255], 1);
    __syncthreads();
    const int v = ncnt[t];
    const int lane = t & 63, wid = t >> 6;
    int incl = v;
#pragma unroll
    for (int o = 1; o <= 32; o <<= 1) {
        int u = __shfl_up(incl, o);
        if (lane >= o) incl += u;
    }
    if (lane == 63) wt[wid] = incl;
    __syncthreads();
    int base = 0;
    for (int w = 0; w < wid; ++w) base += wt[w];
    nbs[t] = base + incl - v;
    const int n = bkt * 256 + t;
    if (n < N) {
        off[n] = gb + nbs[t];
        dis[n] = rsqrtf((float)v + 1.0f);
        if (n == N - 1) off[N] = E;
    }
    __syncthreads();
    for (int i = gb + t; i < ge; i += 256) {
        const unsigned p = pk[i];
        const int dl = (p >> 16) & 255;
        const int r = atomicAdd(&ncur[dl], 1);
        csr[gb + nbs[dl] + r] = (int)(p & 0xFFFFu);
    }
}

// ---------- GEMM: LDS-tiled 64x64, 4x4 micro-tile; fp32 or bf16 input, bf16 output ----------
template <int K, bool INBF16>
__global__ __launch_bounds__(256) void gemm_kernel(const void* __restrict__ in_,
                                                   const float* __restrict__ W,
                                                   unsigned short* __restrict__ out16, int N) {
    __shared__ float xs[64][68];
    __shared__ float Wl[64][64];
    const int t = threadIdx.x;
    const int row0 = blockIdx.x * 64;
    const int cq = t & 15, rq = t >> 4;
    float acc[4][4] = {{0.f}};
    for (int kc = 0; kc < K; kc += 64) {
#pragma unroll
        for (int it = 0; it < 4; ++it) {
            const int idx = it * 256 + t;
            const int r = idx >> 4, c4 = idx & 15;
            const int rr = min(row0 + r, N - 1);
            if constexpr (INBF16) {
                const unsigned short* in16 = (const unsigned short*)in_;
                const ushort4 v = *(const ushort4*)(in16 + (size_t)rr * K + kc + c4 * 4);
                *(float4*)(&xs[r][c4 * 4]) = make_float4(bf2f(v.x), bf2f(v.y), bf2f(v.z), bf2f(v.w));
            } else {
                const float* inf = (const float*)in_;
                *(float4*)(&xs[r][c4 * 4]) = *(const float4*)(inf + (size_t)rr * K + kc + c4 * 4);
            }
            *(float4*)(&Wl[r][c4 * 4]) = *(const float4*)(W + (size_t)(kc + r) * HD + c4 * 4);
        }
        __syncthreads();
#pragma unroll
        for (int k4 = 0; k4 < 16; ++k4) {
            float a[4][4], b[4][4];
#pragma unroll
            for (int i = 0; i < 4; ++i)
                *(float4*)a[i] = *(const float4*)(&xs[rq * 4 + i][k4 * 4]);
#pragma unroll
            for (int kk = 0; kk < 4; ++kk)
                *(float4*)b[kk] = *(const float4*)(&Wl[k4 * 4 + kk][cq * 4]);
#pragma unroll
            for (int kk = 0; kk < 4; ++kk)
#pragma unroll
                for (int i = 0; i < 4; ++i)
#pragma unroll
                    for (int j = 0; j < 4; ++j)
                        acc[i][j] = fmaf(a[i][kk], b[kk][j], acc[i][j]);
        }
        __syncthreads();
    }
#pragma unroll
    for (int i = 0; i < 4; ++i) {
        const int r = row0 + rq * 4 + i;
        if (r < N) {
            ushort4 o;
            o.x = f2bf(acc[i][0]); o.y = f2bf(acc[i][1]);
            o.z = f2bf(acc[i][2]); o.w = f2bf(acc[i][3]);
            *(ushort4*)(out16 + (size_t)r * HD + cq * 4) = o;
        }
    }
}

// ---------- fused aggregation: 8-edge dwordx4 bf16 gathers, prefetch depth 1 ----------
// lane = (g = lane>>3 edge slot 0..7, p = lane&7 h-octet). One wave per node.
__global__ __launch_bounds__(256) void agg_kernel(const int* __restrict__ csr,
                                                  const int* __restrict__ off,
                                                  const float* __restrict__ dis,
                                                  const unsigned short* __restrict__ h16,
                                                  const float* __restrict__ b,
                                                  unsigned short* __restrict__ z16, int N) {
    const int lane = threadIdx.x & 63;
    const int wid  = threadIdx.x >> 6;
    const int n = blockIdx.x * 4 + wid;
    if (n >= N) return;
    const int beg = off[n];
    const int c = min(off[n + 1] - beg, 64);
    int   s_l = 0;
    float w_l = 0.f;
    if (lane < c) {
        s_l = csr[beg + lane];
        w_l = dis[s_l];
    }
    const float dn = dis[n];
    const int g = lane >> 3;
    const int p = lane & 7;
    float a[8];
#pragma unroll
    for (int j = 0; j < 8; ++j) a[j] = 0.f;
    // prefetch edge group 0
    int   sE = __shfl(s_l, g);
    float wE = __shfl(w_l, g);
    uint4 hv = *(const uint4*)(h16 + (size_t)sE * HD + p * 8);
    for (int e = 8; e < c; e += 8) {
        const int   sN = __shfl(s_l, e + g);
        const float wN = __shfl(w_l, e + g);
        const uint4 nv = *(const uint4*)(h16 + (size_t)sN * HD + p * 8);
        const unsigned vv[4] = {hv.x, hv.y, hv.z, hv.w};
#pragma unroll
        for (int q = 0; q < 4; ++q) {
            a[2 * q]     = fmaf(__uint_as_float(vv[q] << 16), wE, a[2 * q]);
            a[2 * q + 1] = fmaf(__uint_as_float(vv[q] & 0xFFFF0000u), wE, a[2 * q + 1]);
        }
        hv = nv; wE = wN;
    }
    {
        const unsigned vv[4] = {hv.x, hv.y, hv.z, hv.w};
#pragma unroll
        for (int q = 0; q < 4; ++q) {
            a[2 * q]     = fmaf(__uint_as_float(vv[q] << 16), wE, a[2 * q]);
            a[2 * q + 1] = fmaf(__uint_as_float(vv[q] & 0xFFFF0000u), wE, a[2 * q + 1]);
        }
    }
#pragma unroll
    for (int st = 8; st <= 32; st <<= 1)
#pragma unroll
        for (int j = 0; j < 8; ++j) a[j] += __shfl_xor(a[j], st);
    if (g == 0) {
        const uint4 sv = *(const uint4*)(h16 + (size_t)n * HD + p * 8);
        const unsigned ss[4] = {sv.x, sv.y, sv.z, sv.w};
        const float4 b0 = *(const float4*)(b + p * 8);
        const float4 b1 = *(const float4*)(b + p * 8 + 4);
        const float bb[8] = {b0.x, b0.y, b0.z, b0.w, b1.x, b1.y, b1.z, b1.w};
        float o[8];
#pragma unroll
        for (int q = 0; q < 4; ++q) {
            o[2 * q]     = a[2 * q]     + __uint_as_float(ss[q] << 16) * dn;
            o[2 * q + 1] = a[2 * q + 1] + __uint_as_float(ss[q] & 0xFFFF0000u) * dn;
        }
#pragma unroll
        for (int j = 0; j < 8; ++j) o[j] = fmaxf(fmaf(o[j], dn, bb[j]), 0.f);
        ushort4 o0, o1;
        o0.x = f2bf(o[0]); o0.y = f2bf(o[1]); o0.z = f2bf(o[2]); o0.w = f2bf(o[3]);
        o1.x = f2bf(o[4]); o1.y = f2bf(o[5]); o1.z = f2bf(o[6]); o1.w = f2bf(o[7]);
        unsigned short* zp = z16 + (size_t)n * HD + p * 8;
        *(ushort4*)zp = o0;
        *(ushort4*)(zp + 4) = o1;
    }
}

// ---------- u/d precompute: u16[n][h][m], d16[n][h][l] (interleaved repack) ----------
__global__ __launch_bounds__(256) void uprep_kernel(const unsigned short* __restrict__ z16,
                                                    const float* __restrict__ Wp,
                                                    ushort4* __restrict__ u16,
                                                    ushort4* __restrict__ d16, int N) {
    const int i = blockIdx.x * blockDim.x + threadIdx.x;
    const int total = N * HD;
    if (i >= total) return;
    const size_t NH = (size_t)N_NODES * HD;
    const unsigned short r0 = z16[0 * NH + i], r1 = z16[1 * NH + i];
    const unsigned short r2 = z16[2 * NH + i], r3 = z16[3 * NH + i];
    ushort4 d;
    d.x = r0; d.y = r1; d.z = r2; d.w = r3;
    d16[i] = d;
    const float z0 = bf2f(r0), z1 = bf2f(r1), z2 = bf2f(r2), z3 = bf2f(r3);
    ushort4 u;
    u.x = f2bf(z0 * Wp[0] + z1 * Wp[4] + z2 * Wp[8]  + z3 * Wp[12]);
    u.y = f2bf(z0 * Wp[1] + z1 * Wp[5] + z2 * Wp[9]  + z3 * Wp[13]);
    u.z = f2bf(z0 * Wp[2] + z1 * Wp[6] + z2 * Wp[10] + z3 * Wp[14]);
    u.w = f2bf(z0 * Wp[3] + z1 * Wp[7] + z2 * Wp[11] + z3 * Wp[15]);
    u16[i] = u;
}

// ---------- link prediction + BCE loss: 8 edges per wave-iteration, 2 gathers/edge ----------
__global__ __launch_bounds__(256) void linkpred_kernel(const ushort4* __restrict__ u16,
                                                       const ushort4* __restrict__ d16,
                                                       const int* __restrict__ pos,
                                                       const int* __restrict__ neg,
                                                       const float* __restrict__ bp,
                                                       double* __restrict__ acc, int EP) {
    const int lane = threadIdx.x & 63;
    const int wid  = threadIdx.x >> 6;
    const float bpv = bp[0];
    int gw = blockIdx.x * 4 + wid;
    const int nw = gridDim.x * 4;
    const int nchunks = (2 * EP) >> 3;
    float lsum = 0.f;
    for (int c0 = gw; c0 < nchunks; c0 += nw) {
        const int c = __builtin_amdgcn_readfirstlane(c0);
        const int i0 = c << 3;
        const bool is_pos = i0 < EP;
        const int* __restrict__ eptr = is_pos ? pos : neg;
        const int jj0 = is_pos ? i0 : i0 - EP;
        float t[8];
#pragma unroll
        for (int k = 0; k < 8; ++k) {
            const int e0 = eptr[jj0 + k];
            const int e1 = eptr[EP + jj0 + k];
            const ushort4 uv = u16[(size_t)e0 * HD + lane];
            const ushort4 dv = d16[(size_t)e1 * HD + lane];
            float s = bf2f(uv.x) * bf2f(dv.x);
            s = fmaf(bf2f(uv.y), bf2f(dv.y), s);
            s = fmaf(bf2f(uv.z), bf2f(dv.z), s);
            s = fmaf(bf2f(uv.w), bf2f(dv.w), s);
            t[k] = s;
        }
#pragma unroll
        for (int st = 1; st <= 32; st <<= 1) {
#pragma unroll
            for (int k = 0; k < 8; ++k) t[k] += __shfl_xor(t[k], st);
        }
        if (lane < 8) {
            float tt = t[0];
            tt = (lane == 1) ? t[1] : tt;
            tt = (lane == 2) ? t[2] : tt;
            tt = (lane == 3) ? t[3] : tt;
            tt = (lane == 4) ? t[4] : tt;
            tt = (lane == 5) ? t[5] : tt;
            tt = (lane == 6) ? t[6] : tt;
            tt = (lane == 7) ? t[7] : tt;
            float logit  = tt + bpv;
            float target = (i0 + lane == EP) ? 1.f : 0.f;
            lsum += fmaxf(logit, 0.f) - logit * target + log1pf(expf(-fabsf(logit)));
        }
    }
#pragma unroll
    for (int o = 32; o >= 1; o >>= 1) lsum += __shfl_xor(lsum, o);
    __shared__ float wsum[4];
    if (lane == 0) wsum[wid] = lsum;
    __syncthreads();
    if (threadIdx.x == 0) {
        double bs = (double)wsum[0] + (double)wsum[1] + (double)wsum[2] + (double)wsum[3];
        atomicAdd(acc, bs);
    }
}

__global__ void loss_final(const double* __restrict__ acc, float* __restrict__ out, int denom) {
    out[0] = (float)(acc[0] / (double)denom);
}

extern "C" void kernel_launch(void* const* d_in, const int* in_sizes, int n_in,
                              void* d_out, int out_size, void* d_ws, size_t ws_size,
                              hipStream_t stream) {
    const float* x   = (const float*)d_in[0];
    const int*   ei  = (const int*)d_in[1];
    const int*   pos = (const int*)d_in[2];
    const int*   neg = (const int*)d_in[3];
    const float* W0  = (const float*)d_in[4];
    const float* b0  = (const float*)d_in[5];
    const float* Wh  = (const float*)d_in[6];
    const float* bh  = (const float*)d_in[7];
    const float* Wp  = (const float*)d_in[8];
    const float* bp  = (const float*)d_in[9];
    const int E  = in_sizes[1] / 2;   // 800000
    const int EP = in_sizes[2] / 2;   // 100000
    const int N  = N_NODES;
    const size_t NH = (size_t)N * HD;

    // ---- workspace layout (256B aligned) ----
    char* ws = (char*)d_ws;
    size_t off_b = 0;
    auto alloc = [&](size_t bytes) { char* p = ws + off_b; off_b = (off_b + bytes + 255) & ~(size_t)255; return p; };
    unsigned short* h16 = (unsigned short*)alloc(NH * sizeof(unsigned short));       // 6.4 MB
    unsigned short* z16 = (unsigned short*)alloc(4 * NH * sizeof(unsigned short));   // 25.6 MB
    ushort4* u16 = (ushort4*)alloc(NH * sizeof(ushort4));                            // 25.6 MB
    ushort4* d16 = (ushort4*)alloc(NH * sizeof(ushort4));                            // 25.6 MB
    float* dis = (float*)alloc((size_t)N * sizeof(float));                           // 200 KB
    int*   off = (int*)alloc((size_t)(N + 1) * sizeof(int));                         // 200 KB
    int*   csr = (int*)alloc((size_t)E * sizeof(int));                               // 3.2 MB
    unsigned* pk = (unsigned*)alloc((size_t)E * sizeof(unsigned));                   // 3.2 MB
    int*   bbase = (int*)alloc((size_t)(NBKT + 1) * sizeof(int));
    int*   gcur  = (int*)alloc((size_t)NBKT * sizeof(int));
    char*  zbase = ws + off_b;
    int*   bcnt = (int*)alloc((size_t)NBKT * sizeof(int));
    double* acc = (double*)alloc(sizeof(double));
    size_t zero_bytes = (size_t)((char*)acc - zbase) + sizeof(double);

    hipMemsetAsync(zbase, 0, zero_bytes, stream);

    const int* src = ei;
    const int* dst = ei + E;

    // CSR build: bucket hist -> scan -> partition -> per-bucket sort (+off, dis)
    bhist_kernel<<<(E + 2047) / 2048, 256, 0, stream>>>(dst, bcnt, E);
    bscan_kernel<<<1, 256, 0, stream>>>(bcnt, bbase, gcur);
    partition_kernel<<<(E + 8191) / 8192, 256, 0, stream>>>(src, dst, gcur, pk, E);
    bsort_kernel<<<NBKT, 256, 0, stream>>>(pk, bbase, off, dis, csr, E, N);

    const int agg_blocks  = (N + 3) / 4;
    const int gemm_blocks = (N + 63) / 64;

    // layer 0
    gemm_kernel<128, false><<<gemm_blocks, 256, 0, stream>>>(x, W0, h16, N);
    agg_kernel<<<agg_blocks, 256, 0, stream>>>(csr, off, dis, h16, b0, z16, N);

    // layers 1..3
    for (int l = 1; l < 4; ++l) {
        unsigned short* zprev = z16 + (size_t)(l - 1) * NH;
        unsigned short* zcur  = z16 + (size_t)l * NH;
        gemm_kernel<64, true><<<gemm_blocks, 256, 0, stream>>>(zprev, Wh + (size_t)(l - 1) * HD * HD, h16, N);
        agg_kernel<<<agg_blocks, 256, 0, stream>>>(csr, off, dis, h16,
                                                   bh + (size_t)(l - 1) * HD, zcur, N);
    }

    // link prediction + loss
    uprep_kernel<<<(N * HD + 255) / 256, 256, 0, stream>>>(z16, Wp, u16, d16, N);
    linkpred_kernel<<<2048, 256, 0, stream>>>(u16, d16, pos, neg, bp, acc, EP);
    loss_final<<<1, 1, 0, stream>>>(acc, (float*)d_out, 2 * EP);
}

// Round 11
// 275.561 us; speedup vs baseline: 2.1062x; 1.0451x over previous
//
#include <hip/hip_runtime.h>
#include <hip/hip_bf16.h>
#include <math.h>

constexpr int N_NODES = 50000;
constexpr int HD = 64;
constexpr int NBKT = (N_NODES + 255) / 256;   // 196 buckets of 256 nodes

typedef float floatx2 __attribute__((ext_vector_type(2)));

__device__ __forceinline__ float bf2f(unsigned short u) {
    return __uint_as_float((unsigned)u << 16);
}
__device__ __forceinline__ unsigned short f2bf(float f) {
    __hip_bfloat16 b = __float2bfloat16(f);
    return *(unsigned short*)&b;
}
// pack 4 floats -> 4 fp8 e4m3 in one dword (bytes 0..3)
__device__ __forceinline__ unsigned pack_fp8x4(float a, float b, float c, float d) {
    unsigned p = __builtin_amdgcn_cvt_pk_fp8_f32(a, b, 0u, false);
    return __builtin_amdgcn_cvt_pk_fp8_f32(c, d, p, true);
}

// ---------- A: bucket histogram (LDS-staged) ----------
__global__ __launch_bounds__(256) void bhist_kernel(const int* __restrict__ dst,
                                                    int* __restrict__ bcnt, int E) {
    __shared__ int lh[256];
    const int t = threadIdx.x;
    lh[t] = 0;
    __syncthreads();
    const int beg = blockIdx.x * 2048;
    const int end = min(beg + 2048, E);
    for (int i = beg + t; i < end; i += 256)
        atomicAdd(&lh[dst[i] >> 8], 1);
    __syncthreads();
    if (t < NBKT && lh[t]) atomicAdd(&bcnt[t], lh[t]);
}

// ---------- B: scan bucket counts -> bbase, init gcur ----------
__global__ __launch_bounds__(256) void bscan_kernel(const int* __restrict__ bcnt,
                                                    int* __restrict__ bbase,
                                                    int* __restrict__ gcur) {
    const int t = threadIdx.x;
    const int v = (t < NBKT) ? bcnt[t] : 0;
    const int lane = t & 63, wid = t >> 6;
    int incl = v;
#pragma unroll
    for (int o = 1; o <= 32; o <<= 1) {
        int u = __shfl_up(incl, o);
        if (lane >= o) incl += u;
    }
    __shared__ int wt[4];
    if (lane == 63) wt[wid] = incl;
    __syncthreads();
    int base = 0;
    for (int w = 0; w < wid; ++w) base += wt[w];
    const int excl = base + incl - v;
    if (t < NBKT) { bbase[t] = excl; gcur[t] = excl; }
    if (t == NBKT - 1) bbase[NBKT] = excl + v;
}

// ---------- C: partition edges into bucket-grouped pk ----------
__global__ __launch_bounds__(256) void partition_kernel(const int* __restrict__ src,
                                                        const int* __restrict__ dst,
                                                        int* __restrict__ gcur,
                                                        unsigned* __restrict__ pk, int E) {
    __shared__ unsigned epk[8192];
    __shared__ int lh[NBKT], lbase[NBKT], lcur[NBKT];
    const int t = threadIdx.x;
    for (int i = t; i < NBKT; i += 256) { lh[i] = 0; lcur[i] = 0; }
    __syncthreads();
    const int beg = blockIdx.x * 8192;
    const int end = min(beg + 8192, E);
    for (int i = beg + t; i < end; i += 256) {
        const int s = src[i], d = dst[i];
        const int bkt = d >> 8;
        epk[i - beg] = ((unsigned)bkt << 24) | ((unsigned)(d & 255) << 16) | (unsigned)s;
        atomicAdd(&lh[bkt], 1);
    }
    __syncthreads();
    for (int i = t; i < NBKT; i += 256)
        if (lh[i]) lbase[i] = atomicAdd(&gcur[i], lh[i]);
    __syncthreads();
    for (int i = beg + t; i < end; i += 256) {
        const unsigned p = epk[i - beg];
        const int bkt = p >> 24;
        const int r = atomicAdd(&lcur[bkt], 1);
        pk[lbase[bkt] + r] = p;
    }
}

// ---------- D: per-bucket counting sort -> csr, off, dis ----------
__global__ __launch_bounds__(256) void bsort_kernel(const unsigned* __restrict__ pk,
                                                    const int* __restrict__ bbase,
                                                    int* __restrict__ off,
                                                    float* __restrict__ dis,
                                                    int* __restrict__ csr, int E, int N) {
    __shared__ int ncnt[256], nbs[256], ncur[256];
    __shared__ int wt[4];
    const int t = threadIdx.x;
    const int bkt = blockIdx.x;
    const int gb = bbase[bkt], ge = bbase[bkt + 1];
    ncnt[t] = 0; ncur[t] = 0;
    __syncthreads();
    for (int i = gb + t; i < ge; i += 256)
        atomicAdd(&ncnt[(pk[i] >> 16) & 255], 1);
    __syncthreads();
    const int v = ncnt[t];
    const int lane = t & 63, wid = t >> 6;
    int incl = v;
#pragma unroll
    for (int o = 1; o <= 32; o <<= 1) {
        int u = __shfl_up(incl, o);
        if (lane >= o) incl += u;
    }
    if (lane == 63) wt[wid] = incl;
    __syncthreads();
    int base = 0;
    for (int w = 0; w < wid; ++w) base += wt[w];
    nbs[t] = base + incl - v;
    const int n = bkt * 256 + t;
    if (n < N) {
        off[n] = gb + nbs[t];
        dis[n] = rsqrtf((float)v + 1.0f);
        if (n == N - 1) off[N] = E;
    }
    __syncthreads();
    for (int i = gb + t; i < ge; i += 256) {
        const unsigned p = pk[i];
        const int dl = (p >> 16) & 255;
        const int r = atomicAdd(&ncur[dl], 1);
        csr[gb + nbs[dl] + r] = (int)(p & 0xFFFFu);
    }
}

// ---------- GEMM: LDS-tiled 64x64, 4x4 micro-tile; emits bf16 h16 + fp8 h8 ----------
template <int K, bool INBF16>
__global__ __launch_bounds__(256) void gemm_kernel(const void* __restrict__ in_,
                                                   const float* __restrict__ W,
                                                   unsigned short* __restrict__ out16,
                                                   unsigned* __restrict__ out8, int N) {
    __shared__ float xs[64][68];
    __shared__ float Wl[64][64];
    const int t = threadIdx.x;
    const int row0 = blockIdx.x * 64;
    const int cq = t & 15, rq = t >> 4;
    float acc[4][4] = {{0.f}};
    for (int kc = 0; kc < K; kc += 64) {
#pragma unroll
        for (int it = 0; it < 4; ++it) {
            const int idx = it * 256 + t;
            const int r = idx >> 4, c4 = idx & 15;
            const int rr = min(row0 + r, N - 1);
            if constexpr (INBF16) {
                const unsigned short* in16 = (const unsigned short*)in_;
                const ushort4 v = *(const ushort4*)(in16 + (size_t)rr * K + kc + c4 * 4);
                *(float4*)(&xs[r][c4 * 4]) = make_float4(bf2f(v.x), bf2f(v.y), bf2f(v.z), bf2f(v.w));
            } else {
                const float* inf = (const float*)in_;
                *(float4*)(&xs[r][c4 * 4]) = *(const float4*)(inf + (size_t)rr * K + kc + c4 * 4);
            }
            *(float4*)(&Wl[r][c4 * 4]) = *(const float4*)(W + (size_t)(kc + r) * HD + c4 * 4);
        }
        __syncthreads();
#pragma unroll
        for (int k4 = 0; k4 < 16; ++k4) {
            float a[4][4], b[4][4];
#pragma unroll
            for (int i = 0; i < 4; ++i)
                *(float4*)a[i] = *(const float4*)(&xs[rq * 4 + i][k4 * 4]);
#pragma unroll
            for (int kk = 0; kk < 4; ++kk)
                *(float4*)b[kk] = *(const float4*)(&Wl[k4 * 4 + kk][cq * 4]);
#pragma unroll
            for (int kk = 0; kk < 4; ++kk)
#pragma unroll
                for (int i = 0; i < 4; ++i)
#pragma unroll
                    for (int j = 0; j < 4; ++j)
                        acc[i][j] = fmaf(a[i][kk], b[kk][j], acc[i][j]);
        }
        __syncthreads();
    }
#pragma unroll
    for (int i = 0; i < 4; ++i) {
        const int r = row0 + rq * 4 + i;
        if (r < N) {
            ushort4 o;
            o.x = f2bf(acc[i][0]); o.y = f2bf(acc[i][1]);
            o.z = f2bf(acc[i][2]); o.w = f2bf(acc[i][3]);
            *(ushort4*)(out16 + (size_t)r * HD + cq * 4) = o;
            out8[(size_t)r * 16 + cq] = pack_fp8x4(acc[i][0], acc[i][1], acc[i][2], acc[i][3]);
        }
    }
}

// ---------- fused aggregation: 8-edge fp8 gathers (64B/edge-row), prefetch depth 1 ----------
// lane = (g = lane>>3 edge slot 0..7, p = lane&7 h-octet). One wave per node.
__global__ __launch_bounds__(256) void agg_kernel(const int* __restrict__ csr,
                                                  const int* __restrict__ off,
                                                  const float* __restrict__ dis,
                                                  const unsigned short* __restrict__ h16,
                                                  const unsigned* __restrict__ h8,
                                                  const float* __restrict__ b,
                                                  unsigned short* __restrict__ z16, int N) {
    const int lane = threadIdx.x & 63;
    const int wid  = threadIdx.x >> 6;
    const int n = blockIdx.x * 4 + wid;
    if (n >= N) return;
    const int beg = off[n];
    const int c = min(off[n + 1] - beg, 64);
    int   s_l = 0;
    float w_l = 0.f;
    if (lane < c) {
        s_l = csr[beg + lane];
        w_l = dis[s_l];
    }
    const float dn = dis[n];
    const int g = lane >> 3;
    const int p = lane & 7;
    float a[8];
#pragma unroll
    for (int j = 0; j < 8; ++j) a[j] = 0.f;
    // prefetch edge group 0
    int   sE = __shfl(s_l, g);
    float wE = __shfl(w_l, g);
    uint2 hv = *(const uint2*)(h8 + (size_t)sE * 16 + p * 2);
    for (int e = 8; e < c; e += 8) {
        const int   sN = __shfl(s_l, e + g);
        const float wN = __shfl(w_l, e + g);
        const uint2 nv = *(const uint2*)(h8 + (size_t)sN * 16 + p * 2);
        floatx2 f01 = __builtin_amdgcn_cvt_pk_f32_fp8(hv.x, false);
        floatx2 f23 = __builtin_amdgcn_cvt_pk_f32_fp8(hv.x, true);
        floatx2 f45 = __builtin_amdgcn_cvt_pk_f32_fp8(hv.y, false);
        floatx2 f67 = __builtin_amdgcn_cvt_pk_f32_fp8(hv.y, true);
        a[0] = fmaf(f01[0], wE, a[0]); a[1] = fmaf(f01[1], wE, a[1]);
        a[2] = fmaf(f23[0], wE, a[2]); a[3] = fmaf(f23[1], wE, a[3]);
        a[4] = fmaf(f45[0], wE, a[4]); a[5] = fmaf(f45[1], wE, a[5]);
        a[6] = fmaf(f67[0], wE, a[6]); a[7] = fmaf(f67[1], wE, a[7]);
        hv = nv; wE = wN;
    }
    {
        floatx2 f01 = __builtin_amdgcn_cvt_pk_f32_fp8(hv.x, false);
        floatx2 f23 = __builtin_amdgcn_cvt_pk_f32_fp8(hv.x, true);
        floatx2 f45 = __builtin_amdgcn_cvt_pk_f32_fp8(hv.y, false);
        floatx2 f67 = __builtin_amdgcn_cvt_pk_f32_fp8(hv.y, true);
        a[0] = fmaf(f01[0], wE, a[0]); a[1] = fmaf(f01[1], wE, a[1]);
        a[2] = fmaf(f23[0], wE, a[2]); a[3] = fmaf(f23[1], wE, a[3]);
        a[4] = fmaf(f45[0], wE, a[4]); a[5] = fmaf(f45[1], wE, a[5]);
        a[6] = fmaf(f67[0], wE, a[6]); a[7] = fmaf(f67[1], wE, a[7]);
    }
#pragma unroll
    for (int st = 8; st <= 32; st <<= 1)
#pragma unroll
        for (int j = 0; j < 8; ++j) a[j] += __shfl_xor(a[j], st);
    if (g == 0) {
        const uint4 sv = *(const uint4*)(h16 + (size_t)n * HD + p * 8);
        const unsigned ss[4] = {sv.x, sv.y, sv.z, sv.w};
        const float4 b0 = *(const float4*)(b + p * 8);
        const float4 b1 = *(const float4*)(b + p * 8 + 4);
        const float bb[8] = {b0.x, b0.y, b0.z, b0.w, b1.x, b1.y, b1.z, b1.w};
        float o[8];
#pragma unroll
        for (int q = 0; q < 4; ++q) {
            o[2 * q]     = a[2 * q]     + __uint_as_float(ss[q] << 16) * dn;
            o[2 * q + 1] = a[2 * q + 1] + __uint_as_float(ss[q] & 0xFFFF0000u) * dn;
        }
#pragma unroll
        for (int j = 0; j < 8; ++j) o[j] = fmaxf(fmaf(o[j], dn, bb[j]), 0.f);
        ushort4 o0, o1;
        o0.x = f2bf(o[0]); o0.y = f2bf(o[1]); o0.z = f2bf(o[2]); o0.w = f2bf(o[3]);
        o1.x = f2bf(o[4]); o1.y = f2bf(o[5]); o1.z = f2bf(o[6]); o1.w = f2bf(o[7]);
        unsigned short* zp = z16 + (size_t)n * HD + p * 8;
        *(ushort4*)zp = o0;
        *(ushort4*)(zp + 4) = o1;
    }
}

// ---------- u/d precompute -> fp8: u8[n*64+h] (4 m-vals), d8[n*64+h] (4 l-vals) ----------
__global__ __launch_bounds__(256) void uprep_kernel(const unsigned short* __restrict__ z16,
                                                    const float* __restrict__ Wp,
                                                    unsigned* __restrict__ u8,
                                                    unsigned* __restrict__ d8, int N) {
    const int i = blockIdx.x * blockDim.x + threadIdx.x;
    const int total = N * HD;
    if (i >= total) return;
    const size_t NH = (size_t)N_NODES * HD;
    const float z0 = bf2f(z16[0 * NH + i]), z1 = bf2f(z16[1 * NH + i]);
    const float z2 = bf2f(z16[2 * NH + i]), z3 = bf2f(z16[3 * NH + i]);
    d8[i] = pack_fp8x4(z0, z1, z2, z3);
    const float u0 = z0 * Wp[0] + z1 * Wp[4] + z2 * Wp[8]  + z3 * Wp[12];
    const float u1 = z0 * Wp[1] + z1 * Wp[5] + z2 * Wp[9]  + z3 * Wp[13];
    const float u2 = z0 * Wp[2] + z1 * Wp[6] + z2 * Wp[10] + z3 * Wp[14];
    const float u3 = z0 * Wp[3] + z1 * Wp[7] + z2 * Wp[11] + z3 * Wp[15];
    u8[i] = pack_fp8x4(u0, u1, u2, u3);
}

// ---------- link prediction + BCE loss: 8 edges per wave-iter, fp8 dword gathers ----------
__global__ __launch_bounds__(256) void linkpred_kernel(const unsigned* __restrict__ u8,
                                                       const unsigned* __restrict__ d8,
                                                       const int* __restrict__ pos,
                                                       const int* __restrict__ neg,
                                                       const float* __restrict__ bp,
                                                       double* __restrict__ acc, int EP) {
    const int lane = threadIdx.x & 63;
    const int wid  = threadIdx.x >> 6;
    const float bpv = bp[0];
    int gw = blockIdx.x * 4 + wid;
    const int nw = gridDim.x * 4;
    const int nchunks = (2 * EP) >> 3;
    float lsum = 0.f;
    for (int c0 = gw; c0 < nchunks; c0 += nw) {
        const int c = __builtin_amdgcn_readfirstlane(c0);
        const int i0 = c << 3;
        const bool is_pos = i0 < EP;
        const int* __restrict__ eptr = is_pos ? pos : neg;
        const int jj0 = is_pos ? i0 : i0 - EP;
        float t[8];
#pragma unroll
        for (int k = 0; k < 8; ++k) {
            const int e0 = eptr[jj0 + k];
            const int e1 = eptr[EP + jj0 + k];
            const unsigned uv = u8[(size_t)e0 * HD + lane];
            const unsigned dv = d8[(size_t)e1 * HD + lane];
            floatx2 ua = __builtin_amdgcn_cvt_pk_f32_fp8(uv, false);
            floatx2 ub = __builtin_amdgcn_cvt_pk_f32_fp8(uv, true);
            floatx2 da = __builtin_amdgcn_cvt_pk_f32_fp8(dv, false);
            floatx2 db = __builtin_amdgcn_cvt_pk_f32_fp8(dv, true);
            float s = ua[0] * da[0];
            s = fmaf(ua[1], da[1], s);
            s = fmaf(ub[0], db[0], s);
            s = fmaf(ub[1], db[1], s);
            t[k] = s;
        }
#pragma unroll
        for (int st = 1; st <= 32; st <<= 1) {
#pragma unroll
            for (int k = 0; k < 8; ++k) t[k] += __shfl_xor(t[k], st);
        }
        if (lane < 8) {
            float tt = t[0];
            tt = (lane == 1) ? t[1] : tt;
            tt = (lane == 2) ? t[2] : tt;
            tt = (lane == 3) ? t[3] : tt;
            tt = (lane == 4) ? t[4] : tt;
            tt = (lane == 5) ? t[5] : tt;
            tt = (lane == 6) ? t[6] : tt;
            tt = (lane == 7) ? t[7] : tt;
            float logit  = tt + bpv;
            float target = (i0 + lane == EP) ? 1.f : 0.f;
            lsum += fmaxf(logit, 0.f) - logit * target + log1pf(expf(-fabsf(logit)));
        }
    }
#pragma unroll
    for (int o = 32; o >= 1; o >>= 1) lsum += __shfl_xor(lsum, o);
    __shared__ float wsum[4];
    if (lane == 0) wsum[wid] = lsum;
    __syncthreads();
    if (threadIdx.x == 0) {
        double bs = (double)wsum[0] + (double)wsum[1] + (double)wsum[2] + (double)wsum[3];
        atomicAdd(acc, bs);
    }
}

__global__ void loss_final(const double* __restrict__ acc, float* __restrict__ out, int denom) {
    out[0] = (float)(acc[0] / (double)denom);
}

extern "C" void kernel_launch(void* const* d_in, const int* in_sizes, int n_in,
                              void* d_out, int out_size, void* d_ws, size_t ws_size,
                              hipStream_t stream) {
    const float* x   = (const float*)d_in[0];
    const int*   ei  = (const int*)d_in[1];
    const int*   pos = (const int*)d_in[2];
    const int*   neg = (const int*)d_in[3];
    const float* W0  = (const float*)d_in[4];
    const float* b0  = (const float*)d_in[5];
    const float* Wh  = (const float*)d_in[6];
    const float* bh  = (const float*)d_in[7];
    const float* Wp  = (const float*)d_in[8];
    const float* bp  = (const float*)d_in[9];
    const int E  = in_sizes[1] / 2;   // 800000
    const int EP = in_sizes[2] / 2;   // 100000
    const int N  = N_NODES;
    const size_t NH = (size_t)N * HD;

    // ---- workspace layout (256B aligned) ----
    char* ws = (char*)d_ws;
    size_t off_b = 0;
    auto alloc = [&](size_t bytes) { char* p = ws + off_b; off_b = (off_b + bytes + 255) & ~(size_t)255; return p; };
    unsigned short* h16 = (unsigned short*)alloc(NH * sizeof(unsigned short));       // 6.4 MB
    unsigned*       h8  = (unsigned*)alloc(NH);                                      // 3.2 MB (1B/elem)
    unsigned short* z16 = (unsigned short*)alloc(4 * NH * sizeof(unsigned short));   // 25.6 MB
    unsigned*       u8  = (unsigned*)alloc(NH * sizeof(unsigned));                   // 12.8 MB
    unsigned*       d8  = (unsigned*)alloc(NH * sizeof(unsigned));                   // 12.8 MB
    float* dis = (float*)alloc((size_t)N * sizeof(float));                           // 200 KB
    int*   off = (int*)alloc((size_t)(N + 1) * sizeof(int));                         // 200 KB
    int*   csr = (int*)alloc((size_t)E * sizeof(int));                               // 3.2 MB
    unsigned* pk = (unsigned*)alloc((size_t)E * sizeof(unsigned));                   // 3.2 MB
    int*   bbase = (int*)alloc((size_t)(NBKT + 1) * sizeof(int));
    int*   gcur  = (int*)alloc((size_t)NBKT * sizeof(int));
    char*  zbase = ws + off_b;
    int*   bcnt = (int*)alloc((size_t)NBKT * sizeof(int));
    double* acc = (double*)alloc(sizeof(double));
    size_t zero_bytes = (size_t)((char*)acc - zbase) + sizeof(double);

    hipMemsetAsync(zbase, 0, zero_bytes, stream);

    const int* src = ei;
    const int* dst = ei + E;

    // CSR build: bucket hist -> scan -> partition -> per-bucket sort (+off, dis)
    bhist_kernel<<<(E + 2047) / 2048, 256, 0, stream>>>(dst, bcnt, E);
    bscan_kernel<<<1, 256, 0, stream>>>(bcnt, bbase, gcur);
    partition_kernel<<<(E + 8191) / 8192, 256, 0, stream>>>(src, dst, gcur, pk, E);
    bsort_kernel<<<NBKT, 256, 0, stream>>>(pk, bbase, off, dis, csr, E, N);

    const int agg_blocks  = (N + 3) / 4;
    const int gemm_blocks = (N + 63) / 64;

    // layer 0
    gemm_kernel<128, false><<<gemm_blocks, 256, 0, stream>>>(x, W0, h16, h8, N);
    agg_kernel<<<agg_blocks, 256, 0, stream>>>(csr, off, dis, h16, h8, b0, z16, N);

    // layers 1..3
    for (int l = 1; l < 4; ++l) {
        unsigned short* zprev = z16 + (size_t)(l - 1) * NH;
        unsigned short* zcur  = z16 + (size_t)l * NH;
        gemm_kernel<64, true><<<gemm_blocks, 256, 0, stream>>>(zprev, Wh + (size_t)(l - 1) * HD * HD, h16, h8, N);
        agg_kernel<<<agg_blocks, 256, 0, stream>>>(csr, off, dis, h16, h8,
                                                   bh + (size_t)(l - 1) * HD, zcur, N);
    }

    // link prediction + loss
    uprep_kernel<<<(N * HD + 255) / 256, 256, 0, stream>>>(z16, Wp, u8, d8, N);
    linkpred_kernel<<<2048, 256, 0, stream>>>(u8, d8, pos, neg, bp, acc, EP);
    loss_final<<<1, 1, 0, stream>>>(acc, (float*)d_out, 2 * EP);
}